// Round 6
// baseline (114.746 us; speedup 1.0000x reference)
//
#include <hip/hip_runtime.h>

// B=8, Cin=64, H=W=128, Cout=64, 9 bilinear taps at (i+0.4, j+0.4) == exact 4x4
// conv with zero pad. Implicit GEMM, bf16 MFMA 16x16x32.
//
// v9: v7 + T14 async-STAGE split. (v8's TLP doubling was null -> revert to v7
//     structure: 128 thr, 2 waves = Cout halves, acc[4][2], 17408 B LDS.)
//   - During the pass-0 stage phase, ALSO load pass-1 data and pack it to
//     bf16 in registers (pk1[8][4] main + ph1[8][4] halo = 64 VGPRs). The
//     pass-1 global latency overlaps pass-0's own stage latency.
//   - After compute-0's barrier, pass-1 staging is pure ds_write (no global
//     ops on the critical path between the two compute phases).
//   - __launch_bounds__(128,3): VGPR cap ~170 (est ~150 used, no spill),
//     3 waves/SIMD. v8 showed waves/SIMD beyond this isn't the constraint.
//   - Same (p, rs, mi, nn) accumulation order -> bitwise-identical output.

#define CIN   64
#define COUT  64
#define HH    128
#define WW    128
#define NC    68    // tile cols: col c <-> global x = x0 - 1 + c, c in [0,66]

typedef __attribute__((ext_vector_type(8))) short bf16x8;   // 8 bf16 = 4 VGPRs
typedef __attribute__((ext_vector_type(4))) float f32x4;
typedef __attribute__((ext_vector_type(4))) unsigned int u32x4;

__device__ __forceinline__ unsigned short f2bf(float f) {
  unsigned int u = __float_as_uint(f);
  u = (u + 0x7fffu + ((u >> 16) & 1u)) >> 16;   // RNE
  return (unsigned short)u;
}

__device__ __forceinline__ unsigned int cvtpk(float lo, float hi) {
  unsigned int r;                                // D = {bf16(lo), bf16(hi)} RNE
  asm("v_cvt_pk_bf16_f32 %0, %1, %2" : "=v"(r) : "v"(lo), "v"(hi));
  return r;
}

// ---------------------------------------------------------------------------
// W4[o][c][r][s] = sum_k w[o,c,k] * cy_k(r-iy_k) * cx_k(s-ix_k).
// Stream layout: wb2[(((p*16+rs)*4 + n)*64 + lane)*8 + j]; consuming lane l
// holds o = n*16 + (l&15), ch = p*32 + (l>>4)*8 + j, for tap rs. (verified)
// ---------------------------------------------------------------------------
__global__ void make_wb(const float* __restrict__ wgt,
                        const float* __restrict__ off,
                        unsigned short* __restrict__ wb2)
{
  int id = blockIdx.x * 64 + threadIdx.x;       // 4096 = 64*64
  int o = id >> 6, c = id & 63;
  float W16[16];
  #pragma unroll
  for (int i = 0; i < 16; ++i) W16[i] = 0.f;
  for (int k = 0; k < 9; ++k) {
    float dy = off[2*k], dx = off[2*k+1];
    float fyf = floorf(dy), fxf = floorf(dx);
    int   iy = (int)fyf,   ix = (int)fxf;       // in {0,1,2}
    float fy = dy - fyf,   fx = dx - fxf;
    float wk = wgt[(o*CIN + c)*9 + k];
    W16[(iy  )*4 + ix  ] += wk * (1.f-fy)*(1.f-fx);
    W16[(iy  )*4 + ix+1] += wk * (1.f-fy)*fx;
    W16[(iy+1)*4 + ix  ] += wk * fy*(1.f-fx);
    W16[(iy+1)*4 + ix+1] += wk * fy*fx;
  }
  int p = c >> 5, q = (c >> 3) & 3, j = c & 7;
  int n = o >> 4, m15 = o & 15;
  int lanei = q*16 + m15;
  for (int rs = 0; rs < 16; ++rs)
    wb2[(size_t)(((p*16 + rs)*4 + n)*64 + lanei)*8 + j] = f2bf(W16[rs]);
}

// ---------------------------------------------------------------------------
// conv: WG = 128 threads (2 waves), tile = 1 out row x 64 px x 64 Cout.
// Wave = 64 px x 32 Cout (wave index = Cout half), acc[4][2].
// LDS: 4 rows x 68 cols x 32 ch bf16, XOR slot swizzle. 17408 B.
// ---------------------------------------------------------------------------
__global__ __launch_bounds__(128, 3)   // VGPR cap ~170: no spill, 3 waves/EU
void conv_mfma(const float* __restrict__ x,
               const unsigned short* __restrict__ wb2,
               float* __restrict__ out)
{
  __shared__ __align__(16) unsigned short tile[4 * NC * 32]; // 17408 B

  const int wg  = blockIdx.x;                   // 2048
  const int xcd = wg & 7;
  const int i   = wg >> 3;                      // 0..255
  const int b   = i >> 5;                       // 0..7
  const int r5  = i & 31;
  const int y0  = xcd * 16 + (r5 >> 1);         // XCD-local 16-row band
  const int x0  = (r5 & 1) * 64;                // x half
  const int t    = threadIdx.x;
  const int wave = t >> 6;                      // 0..1: Cout half
  const int lane = t & 63;
  const int m15  = lane & 15;
  const int q    = lane >> 4;
  const int wv   = __builtin_amdgcn_readfirstlane(wave);

  // ---- per-lane staging constants ----
  int gx   = x0 - 1 + lane;
  bool gxv = ((unsigned)gx < (unsigned)WW);
  int gxc  = gx < 0 ? 0 : (gx > WW-1 ? WW-1 : gx);
  int gxh  = x0 + 63 + lane;                    // halo cols 64..66 (lanes 0..2)
  bool gxhv = ((unsigned)gxh < (unsigned)WW);
  int gxhc = gxh < 0 ? 0 : (gxh > WW-1 ? WW-1 : gxh);

  // LDS store bases: cell(row,col,slot) at row*4352 + col*64 + slot*16 bytes,
  // slot = (chunk + (col>>2)) & 3. Wave's chunks are {wv, wv+2} (j = it&1).
  // Halo col = 64+lane has the same slot phase -> main address + 4096.
  const int w4 = (lane >> 2) & 3;
  char* pst[2];
  pst[0] = (char*)tile + lane*64 + ((wv     + w4) & 3)*16;
  pst[1] = (char*)tile + lane*64 + ((wv + 2 + w4) & 3)*16;

  // A-fragment read pointers: c = mi*16 + m15 + s; slot phase invariant under
  // mi*16 -> aptr[s] + r*4352 + mi*1024 (all-immediate offsets in the rs loop).
  const char* aptr[4];
  #pragma unroll
  for (int s = 0; s < 4; ++s) {
    int c0   = m15 + s;
    int slot = (q + (c0 >> 2)) & 3;
    aptr[s] = (const char*)tile + c0*64 + slot*16;
  }

  f32x4 acc[4][2];
  #pragma unroll
  for (int mi = 0; mi < 4; ++mi)
    #pragma unroll
    for (int nn = 0; nn < 2; ++nn)
      acc[mi][nn] = (f32x4){0.f, 0.f, 0.f, 0.f};

  unsigned int pk1[8][4];                       // pass-1 main, packed bf16
  unsigned int ph1[8][4];                       // pass-1 halo, packed bf16

  // ---- stage pass 0 + prefetch/pack pass 1 (T14) ----
  #pragma unroll
  for (int it = 0; it < 8; ++it) {
    const int row   = it >> 1;
    const int j     = it & 1;
    const int chunk = wv + 2*j;                 // uniform
    const int gy    = y0 + row - 1;             // uniform, -1..129
    char* dst = pst[j] + row*4352;
    if ((unsigned)gy < (unsigned)HH) {          // scalar branch
      const float* ps0 = x + ((size_t)((b*CIN + chunk*8)*HH + gy))*WW;
      const float* ps1 = ps0 + (size_t)32*HH*WW;
      float v0[8], v1[8];
      #pragma unroll
      for (int cc = 0; cc < 8; ++cc) {
        v0[cc] = ps0[(size_t)cc*HH*WW + gxc];
        v1[cc] = ps1[(size_t)cc*HH*WW + gxc];
      }
      unsigned int pk0[4];
      #pragma unroll
      for (int ii = 0; ii < 4; ++ii) {
        pk0[ii]      = cvtpk(v0[2*ii], v0[2*ii+1]);
        pk0[ii]      = gxv ? pk0[ii] : 0u;      // zero-pad col gx==-1/128/129
        pk1[it][ii]  = cvtpk(v1[2*ii], v1[2*ii+1]);
        pk1[it][ii]  = gxv ? pk1[it][ii] : 0u;
      }
      *(u32x4*)dst = *(u32x4*)pk0;
      if (lane < 3) {                           // halo cols 64..66
        float h0[8], h1[8];
        #pragma unroll
        for (int cc = 0; cc < 8; ++cc) {
          h0[cc] = ps0[(size_t)cc*HH*WW + gxhc];
          h1[cc] = ps1[(size_t)cc*HH*WW + gxhc];
        }
        unsigned int q0[4];
        #pragma unroll
        for (int ii = 0; ii < 4; ++ii) {
          q0[ii]      = cvtpk(h0[2*ii], h0[2*ii+1]);
          q0[ii]      = gxhv ? q0[ii] : 0u;
          ph1[it][ii] = cvtpk(h1[2*ii], h1[2*ii+1]);
          ph1[it][ii] = gxhv ? ph1[it][ii] : 0u;
        }
        *(u32x4*)(dst + 4096) = *(u32x4*)q0;
      }
    } else {                                    // OOB row: zero once; kept for pass 1
      *(u32x4*)dst = (u32x4){0u,0u,0u,0u};
      if (lane < 3) *(u32x4*)(dst + 4096) = (u32x4){0u,0u,0u,0u};
    }
  }
  __syncthreads();

  // ---- compute pass 0 ----
  {
    const char* wp = (const char*)wb2 + wave*2048 + (size_t)lane*16;
    #pragma unroll
    for (int rs = 0; rs < 16; ++rs) {
      const int r = rs >> 2, s = rs & 3;
      bf16x8 bfr[2];
      bfr[0] = *(const bf16x8*)(wp + rs*4096);
      bfr[1] = *(const bf16x8*)(wp + rs*4096 + 1024);
      bf16x8 afr[4];
      #pragma unroll
      for (int mi = 0; mi < 4; ++mi)
        afr[mi] = *(const bf16x8*)(aptr[s] + r*4352 + mi*1024);
      #pragma unroll
      for (int mi = 0; mi < 4; ++mi)
        #pragma unroll
        for (int nn = 0; nn < 2; ++nn)
          acc[mi][nn] = __builtin_amdgcn_mfma_f32_16x16x32_bf16(afr[mi], bfr[nn], acc[mi][nn], 0, 0, 0);
    }
  }
  __syncthreads();                              // pass-0 tile reads complete

  // ---- write pass 1 from registers (no global ops) ----
  #pragma unroll
  for (int it = 0; it < 8; ++it) {
    const int row = it >> 1;
    const int j   = it & 1;
    const int gy  = y0 + row - 1;
    if ((unsigned)gy < (unsigned)HH) {
      char* dst = pst[j] + row*4352;
      *(u32x4*)dst = *(u32x4*)pk1[it];
      if (lane < 3) *(u32x4*)(dst + 4096) = *(u32x4*)ph1[it];
    }                                           // OOB rows: LDS still zero
  }
  __syncthreads();

  // ---- compute pass 1 ----
  {
    const char* wp = (const char*)wb2 + 65536 + wave*2048 + (size_t)lane*16;
    #pragma unroll
    for (int rs = 0; rs < 16; ++rs) {
      const int r = rs >> 2, s = rs & 3;
      bf16x8 bfr[2];
      bfr[0] = *(const bf16x8*)(wp + rs*4096);
      bfr[1] = *(const bf16x8*)(wp + rs*4096 + 1024);
      bf16x8 afr[4];
      #pragma unroll
      for (int mi = 0; mi < 4; ++mi)
        afr[mi] = *(const bf16x8*)(aptr[s] + r*4352 + mi*1024);
      #pragma unroll
      for (int mi = 0; mi < 4; ++mi)
        #pragma unroll
        for (int nn = 0; nn < 2; ++nn)
          acc[mi][nn] = __builtin_amdgcn_mfma_f32_16x16x32_bf16(afr[mi], bfr[nn], acc[mi][nn], 0, 0, 0);
    }
  }

  // ---- epilogue: transpose through LDS for coalesced f32x4 stores ----
  __syncthreads();                              // all tile reads done
  float* epi = (float*)tile;                    // [64 o][68 px] f32 = 17408 B
  #pragma unroll
  for (int mi = 0; mi < 4; ++mi)
    #pragma unroll
    for (int nn = 0; nn < 2; ++nn) {
      int o  = (wave*2 + nn)*16 + m15;
      int px = mi*16 + q*4;                     // D row = q*4 + reg
      *(f32x4*)&epi[o*NC + px] = acc[mi][nn];
    }
  __syncthreads();
  #pragma unroll
  for (int round = 0; round < 8; ++round) {
    int idx = round*512 + t*4;                  // 64 o x 64 px
    int o = idx >> 6, px = idx & 63;
    f32x4 v = *(const f32x4*)&epi[o*NC + px];
    *(f32x4*)&out[(((size_t)(b*COUT + o))*HH + y0)*WW + x0 + px] = v;
  }
}

// ---------------------------------------------------------------------------
extern "C" void kernel_launch(void* const* d_in, const int* in_sizes, int n_in,
                              void* d_out, int out_size, void* d_ws, size_t ws_size,
                              hipStream_t stream)
{
  const float* x   = (const float*)d_in[0];   // [8,64,128,128] fp32
  const float* wgt = (const float*)d_in[1];   // [64,64,9] fp32
  const float* off = (const float*)d_in[2];   // [9,2] fp32
  float* out = (float*)d_out;                 // [8,64,128,128] fp32
  unsigned short* wb2 = (unsigned short*)d_ws;// 128 KB stream-layout weights

  make_wb<<<64, 64, 0, stream>>>(wgt, off, wb2);
  conv_mfma<<<2048, 128, 0, stream>>>(x, wb2, out);
}

// Round 7
// 106.663 us; speedup vs baseline: 1.0758x; 1.0758x over previous
//
#include <hip/hip_runtime.h>

// B=8, Cin=64, H=W=128, Cout=64, 9 bilinear taps at (i+0.4, j+0.4) == exact 4x4
// conv with zero pad. Implicit GEMM, bf16 MFMA 16x16x32.
//
// v10: barrier-free single-wave pipeline.
//   - v9 post-mortem: traffic at floor (FETCH 20 MB, WRITE 33 MB) but 2x over
//     time floor; serial stage->syncthreads->compute drains vmcnt(0) at every
//     barrier. Key insight: compute sub-phase r reads ONLY LDS row r ->
//     2-slot row ring suffices; with 1 wave/block the LDS is wave-private and
//     the kernel needs ZERO __syncthreads -> zero waitcnt drains -> compiler
//     free to keep loads/ds/MFMA concurrently in flight.
//   - 2048 blocks x 64 thr; strip = 1 out row x 64 px x 64 Cout (acc[4][4]).
//     8 phases k = (pass p = k>>2, row r = k&3); pipeline per phase:
//     LOAD(k+2)->regs || WRITE(k+1)->LDS ring || COMPUTE(k) from ring.
//     Register staging double-buffered in NAMED arrays (GM0/GM1).
//   - LDS: ring 2 x 68 cols x 32 ch bf16 (8704 B) + epilogue f32 [64][68]
//     (17408 B total) -> 8 blocks/CU co-resident (2 waves/SIMD, cap 256 VGPR).
//   - Same (p, rs, mi, nn) accumulation order -> bitwise-identical output.

#define CIN   64
#define COUT  64
#define HH    128
#define WW    128

typedef __attribute__((ext_vector_type(8))) short bf16x8;   // 8 bf16 = 4 VGPRs
typedef __attribute__((ext_vector_type(4))) float f32x4;
typedef __attribute__((ext_vector_type(4))) unsigned int u32x4;

__device__ __forceinline__ unsigned short f2bf(float f) {
  unsigned int u = __float_as_uint(f);
  u = (u + 0x7fffu + ((u >> 16) & 1u)) >> 16;   // RNE
  return (unsigned short)u;
}

__device__ __forceinline__ unsigned int cvtpk(float lo, float hi) {
  unsigned int r;                                // D = {bf16(lo), bf16(hi)} RNE
  asm("v_cvt_pk_bf16_f32 %0, %1, %2" : "=v"(r) : "v"(lo), "v"(hi));
  return r;
}

// ---------------------------------------------------------------------------
// W4[o][c][r][s] = sum_k w[o,c,k] * cy_k(r-iy_k) * cx_k(s-ix_k).
// Stream layout: wb2[(((p*16+rs)*4 + n)*64 + lane)*8 + j]; consuming lane l
// holds o = n*16 + (l&15), ch = p*32 + (l>>4)*8 + j, for tap rs. (verified)
// ---------------------------------------------------------------------------
__global__ void make_wb(const float* __restrict__ wgt,
                        const float* __restrict__ off,
                        unsigned short* __restrict__ wb2)
{
  int id = blockIdx.x * 64 + threadIdx.x;       // 4096 = 64*64
  int o = id >> 6, c = id & 63;
  float W16[16];
  #pragma unroll
  for (int i = 0; i < 16; ++i) W16[i] = 0.f;
  for (int k = 0; k < 9; ++k) {
    float dy = off[2*k], dx = off[2*k+1];
    float fyf = floorf(dy), fxf = floorf(dx);
    int   iy = (int)fyf,   ix = (int)fxf;       // in {0,1,2}
    float fy = dy - fyf,   fx = dx - fxf;
    float wk = wgt[(o*CIN + c)*9 + k];
    W16[(iy  )*4 + ix  ] += wk * (1.f-fy)*(1.f-fx);
    W16[(iy  )*4 + ix+1] += wk * (1.f-fy)*fx;
    W16[(iy+1)*4 + ix  ] += wk * fy*(1.f-fx);
    W16[(iy+1)*4 + ix+1] += wk * fy*fx;
  }
  int p = c >> 5, q = (c >> 3) & 3, j = c & 7;
  int n = o >> 4, m15 = o & 15;
  int lanei = q*16 + m15;
  for (int rs = 0; rs < 16; ++rs)
    wb2[(size_t)(((p*16 + rs)*4 + n)*64 + lanei)*8 + j] = f2bf(W16[rs]);
}

// ---------------------------------------------------------------------------
// conv: 1 wave per block, strip = 1 out row x 64 px x 64 Cout, no barriers.
// LDS ring: slot(k&1) = 68 cols x 4 chunk-slots x 16 B = 4352 B, XOR swizzle.
// ---------------------------------------------------------------------------
__global__ __launch_bounds__(64, 2)   // VGPR cap 256 (2 waves/EU)
void conv_mfma(const float* __restrict__ x,
               const unsigned short* __restrict__ wb2,
               float* __restrict__ out)
{
  __shared__ __align__(16) char lds[17408];     // ring 2x4352 B; epi f32[64][68]

  const int wg  = blockIdx.x;                   // 2048
  const int xcd = wg & 7;
  const int i   = wg >> 3;                      // 0..255
  const int b   = i >> 5;                       // 0..7
  const int r5  = i & 31;
  const int y0  = xcd * 16 + (r5 >> 1);         // XCD-local 16-row band
  const int x0  = (r5 & 1) * 64;                // x half
  const int lane = threadIdx.x;                 // 0..63
  const int m15  = lane & 15;
  const int q    = lane >> 4;

  // ---- per-lane staging constants ----
  int gx   = x0 - 1 + lane;                     // main col = lane
  bool gxv = ((unsigned)gx < (unsigned)WW);
  int gxc  = gx < 0 ? 0 : (gx > WW-1 ? WW-1 : gx);
  const int he = (lane >> 4) < 3 ? (lane >> 4) : 2;   // halo col 64+he
  int gxh  = x0 + 63 + he;
  bool gxhv = ((unsigned)gxh < (unsigned)WW) && (lane < 48);
  int gxhc = gxh > WW-1 ? WW-1 : gxh;
  const int hp = lane & 15;                     // halo ch-pair: ch = 2hp, 2hp+1
  // halo LDS offset: col 64+he -> col>>2 = 16 -> slot = chunk; chunk = hp>>2
  const int hoff = (64 + he)*64 + ((hp >> 2) & 3)*16 + (hp & 3)*4;

  // main store offsets: cell(col=lane, chunk) at lane*64 + slot*16,
  // slot = (chunk + (lane>>2)) & 3   (XOR swizzle, same as v7)
  int stoff[4];
  #pragma unroll
  for (int c = 0; c < 4; ++c)
    stoff[c] = lane*64 + ((c + (lane >> 2)) & 3)*16;

  // A-frag read offsets: c0 = m15 + s; slot phase invariant under mi*16.
  int aoff[4];
  #pragma unroll
  for (int s = 0; s < 4; ++s) {
    int c0 = m15 + s;
    aoff[s] = c0*64 + ((q + (c0 >> 2)) & 3)*16;
  }

  f32x4 acc[4][4];
  #pragma unroll
  for (int mi = 0; mi < 4; ++mi)
    #pragma unroll
    for (int nn = 0; nn < 4; ++nn)
      acc[mi][nn] = (f32x4){0.f, 0.f, 0.f, 0.f};

  float GM0[32], GM1[32], GH0[2], GH1[2];       // named double buffers

  auto LOADP = [&](int k, float* GM, float* GH) {
    int gy = y0 + (k & 3) - 1;                  // -1..129, wave-uniform
    if ((unsigned)gy < (unsigned)HH) {
      const float* ps = x + ((size_t)((b*CIN + (k >> 2)*32)*HH + gy))*WW;
      #pragma unroll
      for (int cc = 0; cc < 32; ++cc) GM[cc] = ps[(size_t)cc*HH*WW + gxc];
      GH[0] = ps[(size_t)(2*hp    )*HH*WW + gxhc];
      GH[1] = ps[(size_t)(2*hp + 1)*HH*WW + gxhc];
    }                                           // OOB row: GM/GH unused
  };

  auto WRITEP = [&](int k, const float* GM, const float* GH) {
    int gy = y0 + (k & 3) - 1;
    char* base = lds + (k & 1)*4352;
    if ((unsigned)gy < (unsigned)HH) {
      #pragma unroll
      for (int c = 0; c < 4; ++c) {
        unsigned int pk[4];
        #pragma unroll
        for (int w = 0; w < 4; ++w) {
          pk[w] = cvtpk(GM[c*8 + 2*w], GM[c*8 + 2*w + 1]);
          pk[w] = gxv ? pk[w] : 0u;             // zero-pad cols gx==-1/128/129
        }
        *(u32x4*)(base + stoff[c]) = *(u32x4*)pk;
      }
      unsigned int hw = cvtpk(GH[0], GH[1]);
      hw = gxhv ? hw : 0u;
      if (lane < 48) *(unsigned int*)(base + hoff) = hw;
    } else {                                    // OOB row: zeros (both passes)
      #pragma unroll
      for (int c = 0; c < 4; ++c)
        *(u32x4*)(base + stoff[c]) = (u32x4){0u,0u,0u,0u};
      if (lane < 48) *(unsigned int*)(base + hoff) = 0u;
    }
  };

  auto COMPUTE = [&](int k) {
    const char* wpB = (const char*)wb2 + (size_t)(k >> 2)*65536 + (size_t)lane*16;
    const char* ab  = lds + (k & 1)*4352;
    const int r4 = (k & 3)*4;
    #pragma unroll
    for (int s = 0; s < 4; ++s) {
      const char* wrow = wpB + (size_t)(r4 + s)*4096;
      bf16x8 bfr[4], afr[4];
      #pragma unroll
      for (int n = 0; n < 4; ++n)
        bfr[n] = *(const bf16x8*)(wrow + n*1024);
      #pragma unroll
      for (int mi = 0; mi < 4; ++mi)
        afr[mi] = *(const bf16x8*)(ab + aoff[s] + mi*1024);
      #pragma unroll
      for (int mi = 0; mi < 4; ++mi)
        #pragma unroll
        for (int nn = 0; nn < 4; ++nn)
          acc[mi][nn] = __builtin_amdgcn_mfma_f32_16x16x32_bf16(afr[mi], bfr[nn], acc[mi][nn], 0, 0, 0);
    }
  };

  // ---- pipeline: LOAD(k+2) || WRITE(k+1) || COMPUTE(k), 8 phases ----
  LOADP(0, GM0, GH0);
  LOADP(1, GM1, GH1);
  WRITEP(0, GM0, GH0);
  #pragma unroll
  for (int kk = 0; kk < 4; ++kk) {
    if (kk < 3) LOADP(2*kk + 2, GM0, GH0);      // G0's phase-2kk data consumed
    WRITEP(2*kk + 1, GM1, GH1);
    COMPUTE(2*kk);                              // slot 0
    if (kk < 3) {
      LOADP(2*kk + 3, GM1, GH1);
      WRITEP(2*kk + 2, GM0, GH0);
    }
    COMPUTE(2*kk + 1);                          // slot 1
  }

  // ---- epilogue: transpose through LDS (single wave: no barrier), then
  //      fully-coalesced 1KB stores. epi stride 68 f32 = 272 B (16-aligned). ----
  float* epi = (float*)lds;
  #pragma unroll
  for (int mi = 0; mi < 4; ++mi)
    #pragma unroll
    for (int nn = 0; nn < 4; ++nn) {
      int o  = nn*16 + m15;
      int px = mi*16 + q*4;                     // D row = q*4 + reg
      *(f32x4*)&epi[o*68 + px] = acc[mi][nn];
    }
  #pragma unroll
  for (int i2 = 0; i2 < 16; ++i2) {
    int o  = i2*4 + q;
    int px = m15*4;
    f32x4 v = *(const f32x4*)&epi[o*68 + px];
    *(f32x4*)&out[(((size_t)(b*COUT + o))*HH + y0)*WW + x0 + px] = v;
  }
}

// ---------------------------------------------------------------------------
extern "C" void kernel_launch(void* const* d_in, const int* in_sizes, int n_in,
                              void* d_out, int out_size, void* d_ws, size_t ws_size,
                              hipStream_t stream)
{
  const float* x   = (const float*)d_in[0];   // [8,64,128,128] fp32
  const float* wgt = (const float*)d_in[1];   // [64,64,9] fp32
  const float* off = (const float*)d_in[2];   // [9,2] fp32
  float* out = (float*)d_out;                 // [8,64,128,128] fp32
  unsigned short* wb2 = (unsigned short*)d_ws;// 128 KB stream-layout weights

  make_wb<<<64, 64, 0, stream>>>(wgt, off, wb2);
  conv_mfma<<<2048, 64, 0, stream>>>(x, wb2, out);
}